// Round 3
// baseline (466.666 us; speedup 1.0000x reference)
//
#include <hip/hip_runtime.h>
#include <hip/hip_bf16.h>
#include <stdint.h>

typedef __attribute__((ext_vector_type(8))) short short8;
typedef __attribute__((ext_vector_type(8))) unsigned short ushort8;
typedef __attribute__((ext_vector_type(4))) float f32x4;

#define DEVI __device__ __forceinline__

DEVI unsigned short f2bf(float f) {
    union { float f; unsigned int u; } a;
    a.f = f;
    unsigned int u = a.u;
    u += 0x7fffu + ((u >> 16) & 1u);   // RNE
    return (unsigned short)(u >> 16);
}

// async global->LDS, 16B per lane; ldsbase MUST be wave-uniform (HW adds lane*16)
DEVI void stage16(const unsigned short* g, unsigned short* ldsbase) {
    __builtin_amdgcn_global_load_lds(
        (const __attribute__((address_space(1))) void*)(uintptr_t)g,
        (__attribute__((address_space(3))) void*)(uintptr_t)ldsbase,
        16, 0, 0);
}

// ---------------- fused fp32 -> bf16 cast for hs + 4 weights ----------------
__global__ void cast_all(const float* __restrict__ hs, const float* __restrict__ wq,
                         const float* __restrict__ wk, const float* __restrict__ wv,
                         const float* __restrict__ wo, unsigned short* __restrict__ dst) {
    int i = blockIdx.x * blockDim.x + threadIdx.x;   // 8-element unit; total 3145728
    const float* src;
    int local;
    if (i < 1048576) { src = hs; local = i; }
    else {
        int j = i - 1048576;
        int w = j >> 19;
        local = j & 524287;
        src = (w == 0) ? wq : (w == 1) ? wk : (w == 2) ? wv : wo;
    }
    const float4* s = (const float4*)src;
    float4 x = s[2 * local], y = s[2 * local + 1];
    ushort8 o;
    o[0] = f2bf(x.x); o[1] = f2bf(x.y); o[2] = f2bf(x.z); o[3] = f2bf(x.w);
    o[4] = f2bf(y.x); o[5] = f2bf(y.y); o[6] = f2bf(y.z); o[7] = f2bf(y.w);
    *(ushort8*)(dst + 8 * i) = o;
}

// scale * log2(e), baked into Q at projection time (fp32, single bf16 rounding)
#define QSCALE 0.12751879523173862f

// ---------------- fused QKV GEMM, double-buffered LDS pipeline ----------------
// A [4096x2048] bf16, Bstack [6144x2048] bf16 (Wq|Wk|Wv rows). Per 128-n-slice mode:
// mode0 (Q): bf16 row-major, pre-scaled by QSCALE; mode1 (K): bf16 row-major;
// mode2 (V): bf16 transposed per-head vT[b][h][d][s].
__launch_bounds__(256, 3)
__global__ void gemm_qkv(const unsigned short* __restrict__ A, const unsigned short* __restrict__ Bstack,
                         const float* __restrict__ bq, const float* __restrict__ bk,
                         const float* __restrict__ bv, unsigned short* __restrict__ qb,
                         unsigned short* __restrict__ kb, unsigned short* __restrict__ vtb) {
    constexpr int K = 2048;
    __shared__ __align__(16) unsigned short As[2 * 4096];
    __shared__ __align__(16) unsigned short Bs[2 * 4096];
    const int tid = threadIdx.x;
    const int lane = tid & 63, wid = tid >> 6;
    const int quad = lane >> 4, l15 = lane & 15;
    const int m0 = blockIdx.y * 128, n0 = blockIdx.x * 128;
    const int mode = n0 >> 11;
    const int wm = (wid & 1) * 64, wn = (wid >> 1) * 64;

    f32x4 acc[4][4];
#pragma unroll
    for (int i = 0; i < 4; i++)
#pragma unroll
        for (int j = 0; j < 4; j++) acc[i][j] = f32x4{0.f, 0.f, 0.f, 0.f};

    const int s0 = wid * 128 + lane, s1 = s0 + 64;
    const int r0 = s0 >> 2, c0 = (s0 & 3) ^ (r0 & 3);
    const int r1 = s1 >> 2, c1 = (s1 & 3) ^ (r1 & 3);
    const int ldsoffA0 = wid * 1024, ldsoffA1 = wid * 1024 + 512;
    const unsigned short* Ag0 = &A[(m0 + r0) * K + c0 * 8];
    const unsigned short* Ag1 = &A[(m0 + r1) * K + c1 * 8];
    const unsigned short* Bg0 = &Bstack[(n0 + r0) * K + c0 * 8];
    const unsigned short* Bg1 = &Bstack[(n0 + r1) * K + c1 * 8];

    // prologue: tile 0 -> buffer 0
    stage16(Ag0, &As[ldsoffA0]);
    stage16(Ag1, &As[ldsoffA1]);
    stage16(Bg0, &Bs[ldsoffA0]);
    stage16(Bg1, &Bs[ldsoffA1]);

    for (int i = 0; i < 64; i++) {
        const int cur = (i & 1) * 4096;
        asm volatile("s_waitcnt vmcnt(0)" ::: "memory");
        __syncthreads();
        if (i < 63) {
            const int nxt = 4096 - cur;
            const int koff = (i + 1) * 32;
            stage16(Ag0 + koff, &As[nxt + ldsoffA0]);
            stage16(Ag1 + koff, &As[nxt + ldsoffA1]);
            stage16(Bg0 + koff, &Bs[nxt + ldsoffA0]);
            stage16(Bg1 + koff, &Bs[nxt + ldsoffA1]);
        }
        short8 af[4], bfr[4];
#pragma unroll
        for (int mi = 0; mi < 4; mi++) {
            int row = wm + mi * 16 + l15;
            int cc = quad ^ (row & 3);
            af[mi] = *(const short8*)&As[cur + row * 32 + cc * 8];
        }
#pragma unroll
        for (int ni = 0; ni < 4; ni++) {
            int row = wn + ni * 16 + l15;
            int cc = quad ^ (row & 3);
            bfr[ni] = *(const short8*)&Bs[cur + row * 32 + cc * 8];
        }
#pragma unroll
        for (int mi = 0; mi < 4; mi++)
#pragma unroll
            for (int ni = 0; ni < 4; ni++)
                acc[mi][ni] = __builtin_amdgcn_mfma_f32_16x16x32_bf16(af[mi], bfr[ni], acc[mi][ni], 0, 0, 0);
    }

    const float* bias = (mode == 0) ? bq : (mode == 1) ? bk : bv;
#pragma unroll
    for (int mi = 0; mi < 4; mi++) {
#pragma unroll
        for (int ni = 0; ni < 4; ni++) {
            int n = n0 + wn + ni * 16 + l15;
            int nl = n & 2047;
            float bb = bias[nl];
            if (mode == 2) {
                int m_base = m0 + wm + mi * 16 + quad * 4;
                int h = nl >> 7, dd = nl & 127, bbb = m_base >> 11, s = m_base & 2047;
                unsigned int v0 = f2bf(acc[mi][ni][0] + bb) | ((unsigned int)f2bf(acc[mi][ni][1] + bb) << 16);
                unsigned int v1 = f2bf(acc[mi][ni][2] + bb) | ((unsigned int)f2bf(acc[mi][ni][3] + bb) << 16);
                uint2 pk; pk.x = v0; pk.y = v1;
                *(uint2*)&vtb[((bbb * 16 + h) * 128 + dd) * 2048 + s] = pk;
            } else {
                unsigned short* dst = (mode == 0) ? qb : kb;
                float sc = (mode == 0) ? QSCALE : 1.0f;
#pragma unroll
                for (int r = 0; r < 4; r++) {
                    int m = m0 + wm + mi * 16 + quad * 4 + r;
                    dst[m * 2048 + nl] = f2bf((acc[mi][ni][r] + bb) * sc);
                }
            }
        }
    }
}

// ---------------- output projection GEMM (fp32 out), double-buffered ----------------
__launch_bounds__(256, 2)
__global__ void gemm_out(const unsigned short* __restrict__ A, const unsigned short* __restrict__ Bw,
                         const float* __restrict__ bias, float* __restrict__ Cout) {
    constexpr int K = 2048;
    __shared__ __align__(16) unsigned short As[2 * 4096];
    __shared__ __align__(16) unsigned short Bs[2 * 4096];
    const int tid = threadIdx.x;
    const int lane = tid & 63, wid = tid >> 6;
    const int quad = lane >> 4, l15 = lane & 15;
    const int m0 = blockIdx.y * 128, n0 = blockIdx.x * 128;
    const int wm = (wid & 1) * 64, wn = (wid >> 1) * 64;

    f32x4 acc[4][4];
#pragma unroll
    for (int i = 0; i < 4; i++)
#pragma unroll
        for (int j = 0; j < 4; j++) acc[i][j] = f32x4{0.f, 0.f, 0.f, 0.f};

    const int s0 = wid * 128 + lane, s1 = s0 + 64;
    const int r0 = s0 >> 2, c0 = (s0 & 3) ^ (r0 & 3);
    const int r1 = s1 >> 2, c1 = (s1 & 3) ^ (r1 & 3);
    const int ldsoffA0 = wid * 1024, ldsoffA1 = wid * 1024 + 512;
    const unsigned short* Ag0 = &A[(m0 + r0) * K + c0 * 8];
    const unsigned short* Ag1 = &A[(m0 + r1) * K + c1 * 8];
    const unsigned short* Bg0 = &Bw[(n0 + r0) * K + c0 * 8];
    const unsigned short* Bg1 = &Bw[(n0 + r1) * K + c1 * 8];

    stage16(Ag0, &As[ldsoffA0]);
    stage16(Ag1, &As[ldsoffA1]);
    stage16(Bg0, &Bs[ldsoffA0]);
    stage16(Bg1, &Bs[ldsoffA1]);

    for (int i = 0; i < 64; i++) {
        const int cur = (i & 1) * 4096;
        asm volatile("s_waitcnt vmcnt(0)" ::: "memory");
        __syncthreads();
        if (i < 63) {
            const int nxt = 4096 - cur;
            const int koff = (i + 1) * 32;
            stage16(Ag0 + koff, &As[nxt + ldsoffA0]);
            stage16(Ag1 + koff, &As[nxt + ldsoffA1]);
            stage16(Bg0 + koff, &Bs[nxt + ldsoffA0]);
            stage16(Bg1 + koff, &Bs[nxt + ldsoffA1]);
        }
        short8 af[4], bfr[4];
#pragma unroll
        for (int mi = 0; mi < 4; mi++) {
            int row = wm + mi * 16 + l15;
            int cc = quad ^ (row & 3);
            af[mi] = *(const short8*)&As[cur + row * 32 + cc * 8];
        }
#pragma unroll
        for (int ni = 0; ni < 4; ni++) {
            int row = wn + ni * 16 + l15;
            int cc = quad ^ (row & 3);
            bfr[ni] = *(const short8*)&Bs[cur + row * 32 + cc * 8];
        }
#pragma unroll
        for (int mi = 0; mi < 4; mi++)
#pragma unroll
            for (int ni = 0; ni < 4; ni++)
                acc[mi][ni] = __builtin_amdgcn_mfma_f32_16x16x32_bf16(af[mi], bfr[ni], acc[mi][ni], 0, 0, 0);
    }

#pragma unroll
    for (int mi = 0; mi < 4; mi++) {
#pragma unroll
        for (int ni = 0; ni < 4; ni++) {
            int n = n0 + wn + ni * 16 + l15;
            float bb = bias[n];
#pragma unroll
            for (int r = 0; r < 4; r++) {
                int m = m0 + wm + mi * 16 + quad * 4 + r;
                Cout[m * 2048 + n] = acc[mi][ni][r] + bb;
            }
        }
    }
}

// ---------------- fused flash attention (no-online-max softmax) ----------------
// Q arrives pre-scaled by scale*log2(e); scores feed exp2 directly.
__launch_bounds__(256, 3)
__global__ void attn_fused(const unsigned short* __restrict__ Q, const unsigned short* __restrict__ Kb,
                           const unsigned short* __restrict__ VT, const int* __restrict__ mask,
                           unsigned short* __restrict__ Ob) {
    __shared__ __align__(16) unsigned short Ks[64 * 128];     // [key][d]
    __shared__ __align__(16) unsigned short Vs[128 * 64];     // [d][key]
    __shared__ __align__(16) unsigned short Ps[4 * 32 * 72];  // per-wave P, row stride 72

    const int tid = threadIdx.x;
    const int lane = tid & 63, wid = tid >> 6;
    const int quad = lane >> 4, l15 = lane & 15;
    const int qt = blockIdx.x, bh = blockIdx.y;
    const int b = bh >> 4, h = bh & 15;
    const int tok0 = b * 2048 + qt * 128 + wid * 32;

    short8 aq[2][4];
#pragma unroll
    for (int mi = 0; mi < 2; mi++)
#pragma unroll
        for (int c = 0; c < 4; c++)
            aq[mi][c] = *(const short8*)&Q[(tok0 + mi * 16 + l15) * 2048 + h * 128 + c * 32 + quad * 8];

    f32x4 oacc[2][8];
#pragma unroll
    for (int mi = 0; mi < 2; mi++)
#pragma unroll
        for (int c = 0; c < 8; c++) oacc[mi][c] = f32x4{0.f, 0.f, 0.f, 0.f};
    float lacc[2][4] = {{0.f, 0.f, 0.f, 0.f}, {0.f, 0.f, 0.f, 0.f}};

    const unsigned short* Kbase = Kb + b * 2048 * 2048 + h * 128;
    const unsigned short* Vbase = VT + (b * 16 + h) * 128 * 2048;

    const unsigned short* KgP[4];
    const unsigned short* VgP[4];
    unsigned short* ldsK[4];
    unsigned short* ldsV[4];
#pragma unroll
    for (int j = 0; j < 4; j++) {
        int s = wid * 256 + j * 64 + lane;
        int kr = s >> 4, kc = (s & 15) ^ (kr & 7);
        int vr = s >> 3, vc = (s & 7) ^ (vr & 7);
        KgP[j] = Kbase + kr * 2048 + kc * 8;
        VgP[j] = Vbase + vr * 2048 + vc * 8;
        ldsK[j] = &Ks[(wid * 256 + j * 64) * 8];
        ldsV[j] = &Vs[(wid * 256 + j * 64) * 8];
    }
    unsigned short* pw = &Ps[wid * 2304];

    for (int kt = 0; kt < 32; kt++) {
        const int key0 = kt * 64;
        __syncthreads();
#pragma unroll
        for (int j = 0; j < 4; j++) {
            stage16(KgP[j] + key0 * 2048, ldsK[j]);
            stage16(VgP[j] + key0, ldsV[j]);
        }
        int mk[4];
#pragma unroll
        for (int t = 0; t < 4; t++) mk[t] = mask[b * 2048 + key0 + t * 16 + l15];
        asm volatile("s_waitcnt vmcnt(0)" ::: "memory");
        __syncthreads();

        // QK^T: 2 m-frags x 4 key tiles x 4 d-chunks
        f32x4 sc[2][4];
#pragma unroll
        for (int mi = 0; mi < 2; mi++)
#pragma unroll
            for (int t = 0; t < 4; t++) sc[mi][t] = f32x4{0.f, 0.f, 0.f, 0.f};
#pragma unroll
        for (int c = 0; c < 4; c++)
#pragma unroll
            for (int t = 0; t < 4; t++) {
                int row = t * 16 + l15;
                int cc = (4 * c + quad) ^ (row & 7);
                short8 bk = *(const short8*)&Ks[row * 128 + cc * 8];
                sc[0][t] = __builtin_amdgcn_mfma_f32_16x16x32_bf16(aq[0][c], bk, sc[0][t], 0, 0, 0);
                sc[1][t] = __builtin_amdgcn_mfma_f32_16x16x32_bf16(aq[1][c], bk, sc[1][t], 0, 0, 0);
            }

        // softmax numerator; P -> LDS (C layout -> A layout)
#pragma unroll
        for (int mi = 0; mi < 2; mi++)
#pragma unroll
            for (int t = 0; t < 4; t++)
#pragma unroll
                for (int r = 0; r < 4; r++) {
                    float cs = mk[t] ? sc[mi][t][r] : -1e30f;
                    float p = __builtin_amdgcn_exp2f(cs);
                    lacc[mi][r] += p;
                    pw[(mi * 16 + quad * 4 + r) * 72 + t * 16 + l15] = f2bf(p);
                }
        asm volatile("s_waitcnt lgkmcnt(0)" ::: "memory");
        short8 ap[2][2];
#pragma unroll
        for (int mi = 0; mi < 2; mi++)
#pragma unroll
            for (int kk = 0; kk < 2; kk++)
                ap[mi][kk] = *(const short8*)&pw[(mi * 16 + l15) * 72 + kk * 32 + quad * 8];

        // PV: 2 m-frags x 8 d-tiles x 2 k-chunks
#pragma unroll
        for (int kk = 0; kk < 2; kk++)
#pragma unroll
            for (int dt = 0; dt < 8; dt++) {
                int row = dt * 16 + l15;
                int cc = (kk * 4 + quad) ^ (row & 7);
                short8 bv = *(const short8*)&Vs[row * 64 + cc * 8];
                oacc[0][dt] = __builtin_amdgcn_mfma_f32_16x16x32_bf16(ap[0][kk], bv, oacc[0][dt], 0, 0, 0);
                oacc[1][dt] = __builtin_amdgcn_mfma_f32_16x16x32_bf16(ap[1][kk], bv, oacc[1][dt], 0, 0, 0);
            }
    }

    float inv[2][4];
#pragma unroll
    for (int mi = 0; mi < 2; mi++)
#pragma unroll
        for (int r = 0; r < 4; r++) {
            float l = lacc[mi][r];
#pragma unroll
            for (int off = 1; off < 16; off <<= 1) l += __shfl_xor(l, off, 64);
            inv[mi][r] = 1.0f / l;
        }
#pragma unroll
    for (int mi = 0; mi < 2; mi++)
#pragma unroll
        for (int dt = 0; dt < 8; dt++)
#pragma unroll
            for (int r = 0; r < 4; r++) {
                float val = oacc[mi][dt][r] * inv[mi][r];
                Ob[(tok0 + mi * 16 + quad * 4 + r) * 2048 + h * 128 + dt * 16 + l15] = f2bf(val);
            }
}

extern "C" void kernel_launch(void* const* d_in, const int* in_sizes, int n_in,
                              void* d_out, int out_size, void* d_ws, size_t ws_size,
                              hipStream_t stream) {
    const float* hs = (const float*)d_in[0];
    const int* mask = (const int*)d_in[1];
    const float* Wq = (const float*)d_in[2];
    const float* bq = (const float*)d_in[3];
    const float* Wk = (const float*)d_in[4];
    const float* bk = (const float*)d_in[5];
    const float* Wv = (const float*)d_in[6];
    const float* bv = (const float*)d_in[7];
    const float* Wo = (const float*)d_in[8];
    const float* bo = (const float*)d_in[9];

    unsigned short* hsb = (unsigned short*)d_ws;      // [4096][2048] bf16
    unsigned short* wqb = hsb + 8388608;              // [6144][2048] stacked Wq|Wk|Wv
    unsigned short* wob = wqb + 3 * 4194304;          // [2048][2048]
    unsigned short* qb  = wob + 4194304;              // [4096][2048]
    unsigned short* kb  = qb  + 8388608;              // [4096][2048]
    unsigned short* vtb = kb  + 8388608;              // [2][16][128][2048]
    unsigned short* ab  = vtb + 8388608;              // [4096][2048]

    unsigned short* wkb = wqb + 4194304;
    unsigned short* wvb = wkb + 4194304;
    (void)wkb; (void)wvb;

    cast_all<<<12288, 256, 0, stream>>>(hs, Wq, Wk, Wv, Wo, hsb);

    gemm_qkv<<<dim3(48, 32), 256, 0, stream>>>(hsb, wqb, bq, bk, bv, qb, kb, vtb);
    attn_fused<<<dim3(16, 32), 256, 0, stream>>>(qb, kb, vtb, mask, ab);
    gemm_out<<<dim3(16, 32), 256, 0, stream>>>(ab, wob, bo, (float*)d_out);
}

// Round 5
// 400.535 us; speedup vs baseline: 1.1651x; 1.1651x over previous
//
#include <hip/hip_runtime.h>
#include <hip/hip_bf16.h>
#include <stdint.h>

typedef __attribute__((ext_vector_type(8))) short short8;
typedef __attribute__((ext_vector_type(8))) unsigned short ushort8;
typedef __attribute__((ext_vector_type(4))) float f32x4;

#define DEVI __device__ __forceinline__

DEVI unsigned short f2bf(float f) {
    union { float f; unsigned int u; } a;
    a.f = f;
    unsigned int u = a.u;
    u += 0x7fffu + ((u >> 16) & 1u);   // RNE
    return (unsigned short)(u >> 16);
}

// async global->LDS, 16B per lane; ldsbase MUST be wave-uniform (HW adds lane*16)
DEVI void stage16(const unsigned short* g, unsigned short* ldsbase) {
    __builtin_amdgcn_global_load_lds(
        (const __attribute__((address_space(1))) void*)(uintptr_t)g,
        (__attribute__((address_space(3))) void*)(uintptr_t)ldsbase,
        16, 0, 0);
}

// ---------------- fused fp32 -> bf16 cast for hs + 4 weights ----------------
__global__ void cast_all(const float* __restrict__ hs, const float* __restrict__ wq,
                         const float* __restrict__ wk, const float* __restrict__ wv,
                         const float* __restrict__ wo, unsigned short* __restrict__ dst) {
    int i = blockIdx.x * blockDim.x + threadIdx.x;   // 8-element unit; total 3145728
    const float* src;
    int local;
    if (i < 1048576) { src = hs; local = i; }
    else {
        int j = i - 1048576;
        int w = j >> 19;
        local = j & 524287;
        src = (w == 0) ? wq : (w == 1) ? wk : (w == 2) ? wv : wo;
    }
    const float4* s = (const float4*)src;
    float4 x = s[2 * local], y = s[2 * local + 1];
    ushort8 o;
    o[0] = f2bf(x.x); o[1] = f2bf(x.y); o[2] = f2bf(x.z); o[3] = f2bf(x.w);
    o[4] = f2bf(y.x); o[5] = f2bf(y.y); o[6] = f2bf(y.z); o[7] = f2bf(y.w);
    *(ushort8*)(dst + 8 * i) = o;
}

// scale * log2(e), baked into Q at projection time
#define QSCALE 0.12751879523173862f

// ---------------- fused QKV GEMM, double-buffered LDS pipeline ----------------
__launch_bounds__(256, 3)
__global__ void gemm_qkv(const unsigned short* __restrict__ A, const unsigned short* __restrict__ Bstack,
                         const float* __restrict__ bq, const float* __restrict__ bk,
                         const float* __restrict__ bv, unsigned short* __restrict__ qb,
                         unsigned short* __restrict__ kb, unsigned short* __restrict__ vtb) {
    constexpr int K = 2048;
    __shared__ __align__(16) unsigned short As[2 * 4096];
    __shared__ __align__(16) unsigned short Bs[2 * 4096];
    const int tid = threadIdx.x;
    const int lane = tid & 63, wid = tid >> 6;
    const int quad = lane >> 4, l15 = lane & 15;
    const int m0 = blockIdx.y * 128, n0 = blockIdx.x * 128;
    const int mode = n0 >> 11;
    const int wm = (wid & 1) * 64, wn = (wid >> 1) * 64;

    f32x4 acc[4][4];
#pragma unroll
    for (int i = 0; i < 4; i++)
#pragma unroll
        for (int j = 0; j < 4; j++) acc[i][j] = f32x4{0.f, 0.f, 0.f, 0.f};

    const int s0 = wid * 128 + lane, s1 = s0 + 64;
    const int r0 = s0 >> 2, c0 = (s0 & 3) ^ (r0 & 3);
    const int r1 = s1 >> 2, c1 = (s1 & 3) ^ (r1 & 3);
    const int ldsoffA0 = wid * 1024, ldsoffA1 = wid * 1024 + 512;
    const unsigned short* Ag0 = &A[(m0 + r0) * K + c0 * 8];
    const unsigned short* Ag1 = &A[(m0 + r1) * K + c1 * 8];
    const unsigned short* Bg0 = &Bstack[(n0 + r0) * K + c0 * 8];
    const unsigned short* Bg1 = &Bstack[(n0 + r1) * K + c1 * 8];

    stage16(Ag0, &As[ldsoffA0]);
    stage16(Ag1, &As[ldsoffA1]);
    stage16(Bg0, &Bs[ldsoffA0]);
    stage16(Bg1, &Bs[ldsoffA1]);

    for (int i = 0; i < 64; i++) {
        const int cur = (i & 1) * 4096;
        asm volatile("s_waitcnt vmcnt(0)" ::: "memory");
        __syncthreads();
        if (i < 63) {
            const int nxt = 4096 - cur;
            const int koff = (i + 1) * 32;
            stage16(Ag0 + koff, &As[nxt + ldsoffA0]);
            stage16(Ag1 + koff, &As[nxt + ldsoffA1]);
            stage16(Bg0 + koff, &Bs[nxt + ldsoffA0]);
            stage16(Bg1 + koff, &Bs[nxt + ldsoffA1]);
        }
        short8 af[4], bfr[4];
#pragma unroll
        for (int mi = 0; mi < 4; mi++) {
            int row = wm + mi * 16 + l15;
            int cc = quad ^ (row & 3);
            af[mi] = *(const short8*)&As[cur + row * 32 + cc * 8];
        }
#pragma unroll
        for (int ni = 0; ni < 4; ni++) {
            int row = wn + ni * 16 + l15;
            int cc = quad ^ (row & 3);
            bfr[ni] = *(const short8*)&Bs[cur + row * 32 + cc * 8];
        }
#pragma unroll
        for (int mi = 0; mi < 4; mi++)
#pragma unroll
            for (int ni = 0; ni < 4; ni++)
                acc[mi][ni] = __builtin_amdgcn_mfma_f32_16x16x32_bf16(af[mi], bfr[ni], acc[mi][ni], 0, 0, 0);
    }

    const float* bias = (mode == 0) ? bq : (mode == 1) ? bk : bv;
#pragma unroll
    for (int mi = 0; mi < 4; mi++) {
#pragma unroll
        for (int ni = 0; ni < 4; ni++) {
            int n = n0 + wn + ni * 16 + l15;
            int nl = n & 2047;
            float bb = bias[nl];
            if (mode == 2) {
                int m_base = m0 + wm + mi * 16 + quad * 4;
                int h = nl >> 7, dd = nl & 127, bbb = m_base >> 11, s = m_base & 2047;
                unsigned int v0 = f2bf(acc[mi][ni][0] + bb) | ((unsigned int)f2bf(acc[mi][ni][1] + bb) << 16);
                unsigned int v1 = f2bf(acc[mi][ni][2] + bb) | ((unsigned int)f2bf(acc[mi][ni][3] + bb) << 16);
                uint2 pk; pk.x = v0; pk.y = v1;
                *(uint2*)&vtb[((bbb * 16 + h) * 128 + dd) * 2048 + s] = pk;
            } else {
                unsigned short* dst = (mode == 0) ? qb : kb;
                float sc = (mode == 0) ? QSCALE : 1.0f;
#pragma unroll
                for (int r = 0; r < 4; r++) {
                    int m = m0 + wm + mi * 16 + quad * 4 + r;
                    dst[m * 2048 + nl] = f2bf((acc[mi][ni][r] + bb) * sc);
                }
            }
        }
    }
}

// ---------------- output projection GEMM (fp32 out), double-buffered ----------------
__launch_bounds__(256, 2)
__global__ void gemm_out(const unsigned short* __restrict__ A, const unsigned short* __restrict__ Bw,
                         const float* __restrict__ bias, float* __restrict__ Cout) {
    constexpr int K = 2048;
    __shared__ __align__(16) unsigned short As[2 * 4096];
    __shared__ __align__(16) unsigned short Bs[2 * 4096];
    const int tid = threadIdx.x;
    const int lane = tid & 63, wid = tid >> 6;
    const int quad = lane >> 4, l15 = lane & 15;
    const int m0 = blockIdx.y * 128, n0 = blockIdx.x * 128;
    const int wm = (wid & 1) * 64, wn = (wid >> 1) * 64;

    f32x4 acc[4][4];
#pragma unroll
    for (int i = 0; i < 4; i++)
#pragma unroll
        for (int j = 0; j < 4; j++) acc[i][j] = f32x4{0.f, 0.f, 0.f, 0.f};

    const int s0 = wid * 128 + lane, s1 = s0 + 64;
    const int r0 = s0 >> 2, c0 = (s0 & 3) ^ (r0 & 3);
    const int r1 = s1 >> 2, c1 = (s1 & 3) ^ (r1 & 3);
    const int ldsoffA0 = wid * 1024, ldsoffA1 = wid * 1024 + 512;
    const unsigned short* Ag0 = &A[(m0 + r0) * K + c0 * 8];
    const unsigned short* Ag1 = &A[(m0 + r1) * K + c1 * 8];
    const unsigned short* Bg0 = &Bw[(n0 + r0) * K + c0 * 8];
    const unsigned short* Bg1 = &Bw[(n0 + r1) * K + c1 * 8];

    stage16(Ag0, &As[ldsoffA0]);
    stage16(Ag1, &As[ldsoffA1]);
    stage16(Bg0, &Bs[ldsoffA0]);
    stage16(Bg1, &Bs[ldsoffA1]);

    for (int i = 0; i < 64; i++) {
        const int cur = (i & 1) * 4096;
        asm volatile("s_waitcnt vmcnt(0)" ::: "memory");
        __syncthreads();
        if (i < 63) {
            const int nxt = 4096 - cur;
            const int koff = (i + 1) * 32;
            stage16(Ag0 + koff, &As[nxt + ldsoffA0]);
            stage16(Ag1 + koff, &As[nxt + ldsoffA1]);
            stage16(Bg0 + koff, &Bs[nxt + ldsoffA0]);
            stage16(Bg1 + koff, &Bs[nxt + ldsoffA1]);
        }
        short8 af[4], bfr[4];
#pragma unroll
        for (int mi = 0; mi < 4; mi++) {
            int row = wm + mi * 16 + l15;
            int cc = quad ^ (row & 3);
            af[mi] = *(const short8*)&As[cur + row * 32 + cc * 8];
        }
#pragma unroll
        for (int ni = 0; ni < 4; ni++) {
            int row = wn + ni * 16 + l15;
            int cc = quad ^ (row & 3);
            bfr[ni] = *(const short8*)&Bs[cur + row * 32 + cc * 8];
        }
#pragma unroll
        for (int mi = 0; mi < 4; mi++)
#pragma unroll
            for (int ni = 0; ni < 4; ni++)
                acc[mi][ni] = __builtin_amdgcn_mfma_f32_16x16x32_bf16(af[mi], bfr[ni], acc[mi][ni], 0, 0, 0);
    }

#pragma unroll
    for (int mi = 0; mi < 4; mi++) {
#pragma unroll
        for (int ni = 0; ni < 4; ni++) {
            int n = n0 + wn + ni * 16 + l15;
            float bb = bias[n];
#pragma unroll
            for (int r = 0; r < 4; r++) {
                int m = m0 + wm + mi * 16 + quad * 4 + r;
                Cout[m * 2048 + n] = acc[mi][ni][r] + bb;
            }
        }
    }
}

// ---------------- fused flash attention, 512-thread block, double-buffered K/V ----------------
// grid (8 qtiles, 32 b*h); 8 waves x 32 q-rows. Q pre-scaled by scale*log2(e).
// LDS total 110592 B (gfx950 addressable LDS = 163840 B). vmcnt(0) waits on the
// prefetch issued one full compute phase earlier; mask lives in LDS so staging DMAs
// are the only VMEM ops in the loop.
__launch_bounds__(512, 1)
__global__ void attn_fused(const unsigned short* __restrict__ Q, const unsigned short* __restrict__ Kb,
                           const unsigned short* __restrict__ VT, const int* __restrict__ mask,
                           unsigned short* __restrict__ Ob) {
    __shared__ __align__(16) unsigned short Ks[2][64 * 128];   // [buf][key][d]
    __shared__ __align__(16) unsigned short Vs[2][128 * 64];   // [buf][d][key]
    __shared__ __align__(16) unsigned short Ps[8][32 * 72];    // per-wave P, row stride 72
    __shared__ int Ms[2048];

    const int tid = threadIdx.x;
    const int lane = tid & 63, wid = tid >> 6;
    const int quad = lane >> 4, l15 = lane & 15;
    const int qt = blockIdx.x, bh = blockIdx.y;
    const int b = bh >> 4, h = bh & 15;
    const int tok0 = b * 2048 + qt * 256 + wid * 32;

    // mask -> LDS once
    for (int i = tid; i < 2048; i += 512) Ms[i] = mask[b * 2048 + i];

    short8 aq[2][4];
#pragma unroll
    for (int mi = 0; mi < 2; mi++)
#pragma unroll
        for (int c = 0; c < 4; c++)
            aq[mi][c] = *(const short8*)&Q[(tok0 + mi * 16 + l15) * 2048 + h * 128 + c * 32 + quad * 8];

    f32x4 oacc[2][8];
#pragma unroll
    for (int mi = 0; mi < 2; mi++)
#pragma unroll
        for (int c = 0; c < 8; c++) oacc[mi][c] = f32x4{0.f, 0.f, 0.f, 0.f};
    float lacc[2][4] = {{0.f, 0.f, 0.f, 0.f}, {0.f, 0.f, 0.f, 0.f}};

    const unsigned short* Kbase = Kb + b * 2048 * 2048 + h * 128;
    const unsigned short* Vbase = VT + (b * 16 + h) * 128 * 2048;

    // staging: 1024 16B-slots per K tile (64 rows x 16 chunks) and per V tile (128 x 8).
    const unsigned short* KgP[2];
    const unsigned short* VgP[2];
    int ldsKoff[2], ldsVoff[2];
#pragma unroll
    for (int j = 0; j < 2; j++) {
        int s = wid * 128 + j * 64 + lane;
        int kr = s >> 4, kc = (s & 15) ^ (kr & 7);
        int vr = s >> 3, vc = (s & 7) ^ (vr & 7);
        KgP[j] = Kbase + kr * 2048 + kc * 8;
        VgP[j] = Vbase + vr * 2048 + vc * 8;
        ldsKoff[j] = (wid * 128 + j * 64) * 8;
        ldsVoff[j] = (wid * 128 + j * 64) * 8;
    }
    unsigned short* pw = &Ps[wid][0];

    // prologue: tile 0 -> buffer 0
#pragma unroll
    for (int j = 0; j < 2; j++) {
        stage16(KgP[j], &Ks[0][ldsKoff[j]]);
        stage16(VgP[j], &Vs[0][ldsVoff[j]]);
    }

    for (int kt = 0; kt < 32; kt++) {
        const int cur = kt & 1;
        const int key0 = kt * 64;
        asm volatile("s_waitcnt vmcnt(0)" ::: "memory");
        __syncthreads();
        if (kt < 31) {
            const int nb = cur ^ 1;
            const int key0n = key0 + 64;
#pragma unroll
            for (int j = 0; j < 2; j++) {
                stage16(KgP[j] + key0n * 2048, &Ks[nb][ldsKoff[j]]);
                stage16(VgP[j] + key0n, &Vs[nb][ldsVoff[j]]);
            }
        }
        int mk[4];
#pragma unroll
        for (int t = 0; t < 4; t++) mk[t] = Ms[key0 + t * 16 + l15];

        // QK^T: 2 m-frags x 4 key tiles x 4 d-chunks
        f32x4 sc[2][4];
#pragma unroll
        for (int mi = 0; mi < 2; mi++)
#pragma unroll
            for (int t = 0; t < 4; t++) sc[mi][t] = f32x4{0.f, 0.f, 0.f, 0.f};
#pragma unroll
        for (int c = 0; c < 4; c++)
#pragma unroll
            for (int t = 0; t < 4; t++) {
                int row = t * 16 + l15;
                int cc = (4 * c + quad) ^ (row & 7);
                short8 bk = *(const short8*)&Ks[cur][row * 128 + cc * 8];
                sc[0][t] = __builtin_amdgcn_mfma_f32_16x16x32_bf16(aq[0][c], bk, sc[0][t], 0, 0, 0);
                sc[1][t] = __builtin_amdgcn_mfma_f32_16x16x32_bf16(aq[1][c], bk, sc[1][t], 0, 0, 0);
            }

        // softmax numerator; P -> LDS (C layout -> A layout)
#pragma unroll
        for (int mi = 0; mi < 2; mi++)
#pragma unroll
            for (int t = 0; t < 4; t++)
#pragma unroll
                for (int r = 0; r < 4; r++) {
                    float cs = mk[t] ? sc[mi][t][r] : -1e30f;
                    float p = __builtin_amdgcn_exp2f(cs);
                    lacc[mi][r] += p;
                    pw[(mi * 16 + quad * 4 + r) * 72 + t * 16 + l15] = f2bf(p);
                }
        asm volatile("s_waitcnt lgkmcnt(0)" ::: "memory");
        short8 ap[2][2];
#pragma unroll
        for (int mi = 0; mi < 2; mi++)
#pragma unroll
            for (int kk = 0; kk < 2; kk++)
                ap[mi][kk] = *(const short8*)&pw[(mi * 16 + l15) * 72 + kk * 32 + quad * 8];

        // PV: 2 m-frags x 8 d-tiles x 2 k-chunks
#pragma unroll
        for (int kk = 0; kk < 2; kk++)
#pragma unroll
            for (int dt = 0; dt < 8; dt++) {
                int row = dt * 16 + l15;
                int cc = (kk * 4 + quad) ^ (row & 7);
                short8 bv = *(const short8*)&Vs[cur][row * 64 + cc * 8];
                oacc[0][dt] = __builtin_amdgcn_mfma_f32_16x16x32_bf16(ap[0][kk], bv, oacc[0][dt], 0, 0, 0);
                oacc[1][dt] = __builtin_amdgcn_mfma_f32_16x16x32_bf16(ap[1][kk], bv, oacc[1][dt], 0, 0, 0);
            }
    }

    float inv[2][4];
#pragma unroll
    for (int mi = 0; mi < 2; mi++)
#pragma unroll
        for (int r = 0; r < 4; r++) {
            float l = lacc[mi][r];
#pragma unroll
            for (int off = 1; off < 16; off <<= 1) l += __shfl_xor(l, off, 64);
            inv[mi][r] = 1.0f / l;
        }
#pragma unroll
    for (int mi = 0; mi < 2; mi++)
#pragma unroll
        for (int dt = 0; dt < 8; dt++)
#pragma unroll
            for (int r = 0; r < 4; r++) {
                float val = oacc[mi][dt][r] * inv[mi][r];
                Ob[(tok0 + mi * 16 + quad * 4 + r) * 2048 + h * 128 + dt * 16 + l15] = f2bf(val);
            }
}

extern "C" void kernel_launch(void* const* d_in, const int* in_sizes, int n_in,
                              void* d_out, int out_size, void* d_ws, size_t ws_size,
                              hipStream_t stream) {
    const float* hs = (const float*)d_in[0];
    const int* mask = (const int*)d_in[1];
    const float* Wq = (const float*)d_in[2];
    const float* bq = (const float*)d_in[3];
    const float* Wk = (const float*)d_in[4];
    const float* bk = (const float*)d_in[5];
    const float* Wv = (const float*)d_in[6];
    const float* bv = (const float*)d_in[7];
    const float* Wo = (const float*)d_in[8];
    const float* bo = (const float*)d_in[9];

    unsigned short* hsb = (unsigned short*)d_ws;      // [4096][2048] bf16
    unsigned short* wqb = hsb + 8388608;              // [6144][2048] stacked Wq|Wk|Wv
    unsigned short* wob = wqb + 3 * 4194304;          // [2048][2048]
    unsigned short* qb  = wob + 4194304;              // [4096][2048]
    unsigned short* kb  = qb  + 8388608;              // [4096][2048]
    unsigned short* vtb = kb  + 8388608;              // [2][16][128][2048]
    unsigned short* ab  = vtb + 8388608;              // [4096][2048]

    cast_all<<<12288, 256, 0, stream>>>(hs, Wq, Wk, Wv, Wo, hsb);

    gemm_qkv<<<dim3(48, 32), 256, 0, stream>>>(hsb, wqb, bq, bk, bv, qb, kb, vtb);
    attn_fused<<<dim3(8, 32), 512, 0, stream>>>(qb, kb, vtb, mask, ab);
    gemm_out<<<dim3(16, 32), 256, 0, stream>>>(ab, wob, bo, (float*)d_out);
}